// Round 5
// baseline (117.091 us; speedup 1.0000x reference)
//
#include <hip/hip_runtime.h>
#include <hip/hip_bf16.h>

#define N_  16
#define L0_ 2048
#define L1_ 1024
#define D_  128
#define H_  384

// workspace layout (4-byte word offsets)
#define PMQ_0 0        // float4[32][16][128] (m1,m2,am,pad)  = 262144 words
#define PMQ_1 262144   // float4[16][16][128]                 = 131072 words
#define BASE_ 393216   // float [2][16][128]                  = 4096
#define WBF_  397312   // bf16 [2][128][128] = 16384 words
#define HCNT_ 413696   // int [1536]
#define HLIST_ 415232  // int [1536][128][2] = 393216 words (ends 808448)
#define XBF_  819200   // bf16 x0 then x1 (6,291,456 shorts = 3,145,728 words)

typedef float  floatx4  __attribute__((ext_vector_type(4)));
typedef __bf16 bf16x8   __attribute__((ext_vector_type(8)));
typedef unsigned short ushortx8 __attribute__((ext_vector_type(8)));
typedef unsigned short ushortx4 __attribute__((ext_vector_type(4)));

__device__ __forceinline__ unsigned short f2bf(float f) {
  union { float f; unsigned int u; } v; v.f = f;
  unsigned int u = v.u;
  return (unsigned short)((u + 0x7fffu + ((u >> 16) & 1u)) >> 16);  // RNE
}

// ---------------------------------------------------------------------------
// Kernel 1: partial (top1, top2, argmax) per (tensor, n, d) over 64-row chunks
// AND bf16 staging of x (NT loads: x is read-once; xbf stays L2-resident).
// grid 770: x0 -> 512, x1 -> 256, W0/W1 bf16 conv -> 2.
// ---------------------------------------------------------------------------
__global__ __launch_bounds__(256) void stats_kernel(
    const float* __restrict__ x0, const float* __restrict__ x1,
    const float* __restrict__ W0, const float* __restrict__ W1,
    float* __restrict__ ws) {
  __shared__ float sm1[8][128], sm2[8][128];
  __shared__ int   sam[8][128];
  int bid = blockIdx.x, tid = threadIdx.x;

  if (bid >= 768) {       // bf16 conversion of W[:,0:128] (independent of stats)
    int g = bid - 768;
    const float* W = g ? W1 : W0;
    unsigned short* wbf = (unsigned short*)(ws + WBF_) + g * 16384;
#pragma unroll 4
    for (int it = 0; it < 64; it++) {
      int f = tid + 256 * it;
      wbf[f] = f2bf(W[(size_t)(f >> 7) * H_ + (f & 127)]);
    }
    return;
  }

  const float* x; int n, chunk, L; floatx4* pmq;
  unsigned short* xbf;
  if (bid < 512) {
    x = x0; n = bid >> 5; chunk = bid & 31; L = L0_;
    pmq = (floatx4*)(ws + PMQ_0);
    xbf = (unsigned short*)(ws + XBF_);
  } else {
    int b = bid - 512;
    x = x1; n = b >> 4; chunk = b & 15; L = L1_;
    pmq = (floatx4*)(ws + PMQ_1);
    xbf = (unsigned short*)(ws + XBF_) + (size_t)N_ * L0_ * D_;
  }
  int q = tid & 31, sub = tid >> 5;
  int lbase = chunk * 64 + sub * 8;
  const float* xp = x + (size_t)(n * L + lbase) * D_ + q * 4;
  unsigned short* xbp = xbf + (size_t)(n * L + lbase) * D_ + q * 4;

  float m1[4], m2[4]; int am[4];
#pragma unroll
  for (int j = 0; j < 4; j++) { m1[j] = -3.4e38f; m2[j] = -3.4e38f; am[j] = 0; }
#pragma unroll
  for (int r = 0; r < 8; r++) {
    floatx4 v = __builtin_nontemporal_load((const floatx4*)(xp + (size_t)r * D_));
    // bf16 staging write (same RNE the GEMM applies -> bit-identical y)
    ushortx4 bv = { f2bf(v[0]), f2bf(v[1]), f2bf(v[2]), f2bf(v[3]) };
    *(ushortx4*)(xbp + (size_t)r * D_) = bv;
    int l = lbase + r;
#pragma unroll
    for (int j = 0; j < 4; j++) {
      float vj = v[j];
      if (vj > m1[j]) { m2[j] = m1[j]; m1[j] = vj; am[j] = l; }
      else if (vj > m2[j]) m2[j] = vj;
    }
  }
#pragma unroll
  for (int j = 0; j < 4; j++) {
    int d = q * 4 + j;
    sm1[sub][d] = m1[j]; sm2[sub][d] = m2[j]; sam[sub][d] = am[j];
  }
  __syncthreads();
  if (tid < 128) {
    int d = tid;
    float M1 = sm1[0][d], M2 = sm2[0][d]; int AM = sam[0][d];
#pragma unroll
    for (int s = 1; s < 8; s++) {
      float c1 = sm1[s][d];
      if (c1 > M1) { M2 = fmaxf(M1, sm2[s][d]); M1 = c1; AM = sam[s][d]; }
      else M2 = fmaxf(M2, c1);
    }
    floatx4 outv = { M1, M2, __int_as_float(AM), 0.f };
    pmq[(chunk * N_ + n) * D_ + d] = outv;
  }
}

// ---------------------------------------------------------------------------
// Kernel 2: per-(g,n) prep — merge partials (1 float4/chunk), base GEMV,
// per-32-row-tile hit lists (1536 tiles). grid 32 (g*16+n), 256 threads.
// ---------------------------------------------------------------------------
__global__ __launch_bounds__(256) void prep_kernel(
    const float* __restrict__ W0, const float* __restrict__ b0,
    const float* __restrict__ W1, const float* __restrict__ b1,
    float* __restrict__ ws) {
  __shared__ float t1a[128], t1b[128], sdl[128], bpart[128];
  __shared__ int   sam2[128], scnt[64];
  int bid = blockIdx.x, tid = threadIdx.x;
  int g = bid >> 4, n = bid & 15;
  const float* W = g ? W1 : W0;
  const float* bias = g ? b1 : b0;

  if (tid < 64) scnt[tid] = 0;

  if (tid < 128) {        // merge x0 partials (32 chunks)
    int d = tid;
    const floatx4* pmq = (const floatx4*)(ws + PMQ_0);
    floatx4 v = pmq[n * D_ + d];
    float M1 = v[0], M2 = v[1]; int AM = __float_as_int(v[2]);
#pragma unroll 8
    for (int c = 1; c < 32; c++) {
      floatx4 u = pmq[(c * N_ + n) * D_ + d];
      float c1 = u[0];
      if (c1 > M1) { M2 = fmaxf(M1, u[1]); M1 = c1; AM = __float_as_int(u[2]); }
      else M2 = fmaxf(M2, c1);
    }
    t1a[d] = M1;
    if (g == 0) { sdl[d] = M2 - M1; sam2[d] = AM; }
  } else {                // merge x1 partials (16 chunks)
    int d = tid - 128;
    const floatx4* pmq = (const floatx4*)(ws + PMQ_1);
    floatx4 v = pmq[n * D_ + d];
    float M1 = v[0], M2 = v[1]; int AM = __float_as_int(v[2]);
#pragma unroll 8
    for (int c = 1; c < 16; c++) {
      floatx4 u = pmq[(c * N_ + n) * D_ + d];
      float c1 = u[0];
      if (c1 > M1) { M2 = fmaxf(M1, u[1]); M1 = c1; AM = __float_as_int(u[2]); }
      else M2 = fmaxf(M2, c1);
    }
    t1b[d] = M1;
    if (g == 1) { sdl[d] = M2 - M1; sam2[d] = AM; }
  }
  __syncthreads();

  // base[g][n][o] = bias[o] + t1a.W[o,128:256] + t1b.W[o,256:384]  (fp32-exact)
  int o = tid & 127, half = tid >> 7;
  {
    const float* wr = W + (size_t)o * H_ + 128 + half * 128;
    const float* tv = half ? t1b : t1a;
    float bsum = 0.f;
#pragma unroll 4
    for (int d = 0; d < 128; d += 4) {
      float4 wv = *(const float4*)(wr + d);
      bsum += tv[d] * wv.x + tv[d + 1] * wv.y + tv[d + 2] * wv.z + tv[d + 3] * wv.w;
    }
    if (half) { bpart[o] = bsum; }
    __syncthreads();
    if (!half) ws[BASE_ + (g * N_ + n) * D_ + o] = bias[o] + bsum + bpart[o];
  }

  // scatter LOO corrections into per-32-row-tile lists
  if (tid < 128) {
    int d = tid; int am = sam2[d]; float dl = sdl[d];
    int t = am >> 5;
    int slot = atomicAdd(&scnt[t], 1);
    int tile = (g == 0) ? (n * 64 + t) : (1024 + n * 32 + t);
    int* hl = (int*)ws + HLIST_ + tile * 256;
    hl[slot * 2]     = (am & 31) | (d << 8);
    hl[slot * 2 + 1] = __float_as_int(dl);
  }
  __syncthreads();
  int tcount = g ? 32 : 64;
  if (tid < tcount) {
    int tile = (g == 0) ? (n * 64 + tid) : (1024 + n * 32 + tid);
    ((int*)ws)[HCNT_ + tile] = scnt[tid];
  }
}

// ---------------------------------------------------------------------------
// Kernel 3: GEMM. 32-row tiles, grid 1536, 4 waves/block -> 6 blocks/CU
// (24 waves/CU, 2x the TLP of the 64-row version; inner loop is L2-latency
// bound so occupancy is the lever). Wave = 16 rows x 64 cols, acc[4].
// Swapped MFMA operands (D=[o][xrow]) -> nontemporal dwordx4 y stores.
// ---------------------------------------------------------------------------
__global__ __launch_bounds__(256, 6) void gemm_kernel(
    const float* __restrict__ W0, const float* __restrict__ W1,
    float* __restrict__ out, const float* __restrict__ ws) {
  int bid = blockIdx.x, tid = threadIdx.x;
  int g, n, r0, L; const float* W; float* y; const unsigned short* xbf;
  if (bid < 1024) {
    g = 0; n = bid >> 6; r0 = (bid & 63) << 5; L = L0_; W = W0; y = out;
    xbf = (const unsigned short*)(ws + XBF_);
  } else {
    int b = bid - 1024; g = 1; n = b >> 5; r0 = (b & 31) << 5; L = L1_; W = W1;
    y = out + (size_t)N_ * L0_ * D_;
    xbf = (const unsigned short*)(ws + XBF_) + (size_t)N_ * L0_ * D_;
  }

  int w = tid >> 6, lane = tid & 63, lm = lane & 15, lq = lane >> 4;
  int rsub = (w & 1) << 4, cw = (w >> 1) << 6;

  // hoisted scalars
  int hc = ((const int*)ws)[HCNT_ + bid];
  const int* hl = (const int*)ws + HLIST_ + bid * 256;

  const unsigned short* wbf = (const unsigned short*)(ws + WBF_) + g * 16384;
  const unsigned short* xb = xbf + (size_t)(n * L + r0 + rsub) * D_;

  floatx4 acc[4];
#pragma unroll
  for (int j = 0; j < 4; j++) acc[j] = (floatx4){0.f, 0.f, 0.f, 0.f};

#pragma unroll 2
  for (int kk = 0; kk < 4; kk++) {
    int ko = kk * 32 + lq * 8;
    bf16x8 af = __builtin_bit_cast(bf16x8,              // x rows -> B operand
        *(const ushortx8*)(xb + (size_t)lm * D_ + ko));
    bf16x8 bfr[4];                                       // W rows -> A operand
#pragma unroll
    for (int j = 0; j < 4; j++)
      bfr[j] = __builtin_bit_cast(bf16x8,
          *(const ushortx8*)&wbf[(cw + j * 16 + lm) * 128 + ko]);
#pragma unroll
    for (int j = 0; j < 4; j++)
      acc[j] = __builtin_amdgcn_mfma_f32_16x16x32_bf16(bfr[j], af, acc[j], 0, 0, 0);
  }

  // sparse LOO corrections (fp32-exact). acc[j][r] covers
  // y[rsub+lm][cw+j*16+lq*4+r]; all acc indices compile-time (rule 20).
  int off = 128 + (g << 7);
  for (int k = 0; k < hc; k++) {
    int e = hl[2 * k]; float dl = __int_as_float(hl[2 * k + 1]);
    int row = e & 255, d = e >> 8;
    if (row - rsub == lm) {
#pragma unroll
      for (int j = 0; j < 4; j++)
#pragma unroll
        for (int r = 0; r < 4; r++)
          acc[j][r] += dl * W[(size_t)(cw + j * 16 + lq * 4 + r) * H_ + off + d];
    }
  }

  // epilogue: base add (loaded late to cut mid-loop VGPR pressure) + NT store
  const float* bp = ws + BASE_ + (g * N_ + n) * D_;
  float* yb = y + (size_t)(n * L + r0 + rsub) * D_;
#pragma unroll
  for (int j = 0; j < 4; j++) {
    floatx4 bbj = *(const floatx4*)&bp[cw + j * 16 + lq * 4];
    floatx4 v = acc[j] + bbj;
    __builtin_nontemporal_store(v,
        (floatx4*)&yb[(size_t)lm * D_ + cw + j * 16 + lq * 4]);
  }
}

extern "C" void kernel_launch(void* const* d_in, const int* in_sizes, int n_in,
                              void* d_out, int out_size, void* d_ws, size_t ws_size,
                              hipStream_t stream) {
  const float* x0 = (const float*)d_in[0];
  const float* x1 = (const float*)d_in[1];
  const float* W0 = (const float*)d_in[2];
  const float* b0 = (const float*)d_in[3];
  const float* W1 = (const float*)d_in[4];
  const float* b1 = (const float*)d_in[5];
  float* out = (float*)d_out;
  float* ws  = (float*)d_ws;

  hipLaunchKernelGGL(stats_kernel, dim3(770), dim3(256), 0, stream, x0, x1, W0, W1, ws);
  hipLaunchKernelGGL(prep_kernel,  dim3(32),  dim3(256), 0, stream, W0, b0, W1, b1, ws);
  hipLaunchKernelGGL(gemm_kernel,  dim3(1536), dim3(256), 0, stream, W0, W1, out, ws);
}

// Round 7
// 112.282 us; speedup vs baseline: 1.0428x; 1.0428x over previous
//
#include <hip/hip_runtime.h>
#include <hip/hip_bf16.h>

#define N_  16
#define L0_ 2048
#define L1_ 1024
#define D_  128
#define H_  384

// workspace layout (4-byte word offsets)
#define PMQ_0 0        // float4[32][16][128] (m1,m2,am,pad)  = 262144 words
#define PMQ_1 262144   // float4[16][16][128]                 = 131072 words
#define BASE_ 393216   // float [2][16][128]                  = 4096
#define WBF_  397312   // bf16 [2][128][128] = 16384 words
#define HCNT_ 413696   // int [768]
#define HLIST_ 414464  // int [768][128][2] = 196608 words
#define XBF_  655360   // bf16 x0 then x1 (6,291,456 shorts = 3,145,728 words)

typedef float  floatx4  __attribute__((ext_vector_type(4)));
typedef __bf16 bf16x8   __attribute__((ext_vector_type(8)));
typedef unsigned short ushortx8 __attribute__((ext_vector_type(8)));
typedef unsigned short ushortx4 __attribute__((ext_vector_type(4)));

__device__ __forceinline__ unsigned short f2bf(float f) {
  union { float f; unsigned int u; } v; v.f = f;
  unsigned int u = v.u;
  return (unsigned short)((u + 0x7fffu + ((u >> 16) & 1u)) >> 16);  // RNE
}

// ---------------------------------------------------------------------------
// Kernel 1: partial (top1, top2, argmax) per (tensor, n, d) over 64-row chunks
// AND bf16 staging of x (NT loads: x is read-once; xbf stays L2-resident).
// grid 770: x0 -> 512, x1 -> 256, W0/W1 bf16 conv -> 2.
// ---------------------------------------------------------------------------
__global__ __launch_bounds__(256) void stats_kernel(
    const float* __restrict__ x0, const float* __restrict__ x1,
    const float* __restrict__ W0, const float* __restrict__ W1,
    float* __restrict__ ws) {
  __shared__ float sm1[8][128], sm2[8][128];
  __shared__ int   sam[8][128];
  int bid = blockIdx.x, tid = threadIdx.x;

  if (bid >= 768) {       // bf16 conversion of W[:,0:128] (independent of stats)
    int g = bid - 768;
    const float* W = g ? W1 : W0;
    unsigned short* wbf = (unsigned short*)(ws + WBF_) + g * 16384;
#pragma unroll 4
    for (int it = 0; it < 64; it++) {
      int f = tid + 256 * it;
      wbf[f] = f2bf(W[(size_t)(f >> 7) * H_ + (f & 127)]);
    }
    return;
  }

  const float* x; int n, chunk, L; floatx4* pmq;
  unsigned short* xbf;
  if (bid < 512) {
    x = x0; n = bid >> 5; chunk = bid & 31; L = L0_;
    pmq = (floatx4*)(ws + PMQ_0);
    xbf = (unsigned short*)(ws + XBF_);
  } else {
    int b = bid - 512;
    x = x1; n = b >> 4; chunk = b & 15; L = L1_;
    pmq = (floatx4*)(ws + PMQ_1);
    xbf = (unsigned short*)(ws + XBF_) + (size_t)N_ * L0_ * D_;
  }
  int q = tid & 31, sub = tid >> 5;
  int lbase = chunk * 64 + sub * 8;
  const float* xp = x + (size_t)(n * L + lbase) * D_ + q * 4;
  unsigned short* xbp = xbf + (size_t)(n * L + lbase) * D_ + q * 4;

  float m1[4], m2[4]; int am[4];
#pragma unroll
  for (int j = 0; j < 4; j++) { m1[j] = -3.4e38f; m2[j] = -3.4e38f; am[j] = 0; }
#pragma unroll
  for (int r = 0; r < 8; r++) {
    floatx4 v = __builtin_nontemporal_load((const floatx4*)(xp + (size_t)r * D_));
    // bf16 staging write (same RNE the GEMM applies -> bit-identical y)
    ushortx4 bv = { f2bf(v[0]), f2bf(v[1]), f2bf(v[2]), f2bf(v[3]) };
    *(ushortx4*)(xbp + (size_t)r * D_) = bv;
    int l = lbase + r;
#pragma unroll
    for (int j = 0; j < 4; j++) {
      float vj = v[j];
      if (vj > m1[j]) { m2[j] = m1[j]; m1[j] = vj; am[j] = l; }
      else if (vj > m2[j]) m2[j] = vj;
    }
  }
#pragma unroll
  for (int j = 0; j < 4; j++) {
    int d = q * 4 + j;
    sm1[sub][d] = m1[j]; sm2[sub][d] = m2[j]; sam[sub][d] = am[j];
  }
  __syncthreads();
  if (tid < 128) {
    int d = tid;
    float M1 = sm1[0][d], M2 = sm2[0][d]; int AM = sam[0][d];
#pragma unroll
    for (int s = 1; s < 8; s++) {
      float c1 = sm1[s][d];
      if (c1 > M1) { M2 = fmaxf(M1, sm2[s][d]); M1 = c1; AM = sam[s][d]; }
      else M2 = fmaxf(M2, c1);
    }
    floatx4 outv = { M1, M2, __int_as_float(AM), 0.f };
    pmq[(chunk * N_ + n) * D_ + d] = outv;
  }
}

// ---------------------------------------------------------------------------
// Kernel 2: per-(g,n) prep — merge partials (1 float4/chunk), base GEMV,
// per-64-row-tile hit lists (768 tiles). grid 32 (g*16+n), 256 threads.
// ---------------------------------------------------------------------------
__global__ __launch_bounds__(256) void prep_kernel(
    const float* __restrict__ W0, const float* __restrict__ b0,
    const float* __restrict__ W1, const float* __restrict__ b1,
    float* __restrict__ ws) {
  __shared__ float t1a[128], t1b[128], sdl[128], bpart[128];
  __shared__ int   sam2[128], scnt[32];
  int bid = blockIdx.x, tid = threadIdx.x;
  int g = bid >> 4, n = bid & 15;
  const float* W = g ? W1 : W0;
  const float* bias = g ? b1 : b0;

  if (tid < 32) scnt[tid] = 0;

  if (tid < 128) {        // merge x0 partials (32 chunks)
    int d = tid;
    const floatx4* pmq = (const floatx4*)(ws + PMQ_0);
    floatx4 v = pmq[n * D_ + d];
    float M1 = v[0], M2 = v[1]; int AM = __float_as_int(v[2]);
#pragma unroll 8
    for (int c = 1; c < 32; c++) {
      floatx4 u = pmq[(c * N_ + n) * D_ + d];
      float c1 = u[0];
      if (c1 > M1) { M2 = fmaxf(M1, u[1]); M1 = c1; AM = __float_as_int(u[2]); }
      else M2 = fmaxf(M2, c1);
    }
    t1a[d] = M1;
    if (g == 0) { sdl[d] = M2 - M1; sam2[d] = AM; }
  } else {                // merge x1 partials (16 chunks)
    int d = tid - 128;
    const floatx4* pmq = (const floatx4*)(ws + PMQ_1);
    floatx4 v = pmq[n * D_ + d];
    float M1 = v[0], M2 = v[1]; int AM = __float_as_int(v[2]);
#pragma unroll 8
    for (int c = 1; c < 16; c++) {
      floatx4 u = pmq[(c * N_ + n) * D_ + d];
      float c1 = u[0];
      if (c1 > M1) { M2 = fmaxf(M1, u[1]); M1 = c1; AM = __float_as_int(u[2]); }
      else M2 = fmaxf(M2, c1);
    }
    t1b[d] = M1;
    if (g == 1) { sdl[d] = M2 - M1; sam2[d] = AM; }
  }
  __syncthreads();

  // base[g][n][o] = bias[o] + t1a.W[o,128:256] + t1b.W[o,256:384]  (fp32-exact)
  int o = tid & 127, half = tid >> 7;
  {
    const float* wr = W + (size_t)o * H_ + 128 + half * 128;
    const float* tv = half ? t1b : t1a;
    float bsum = 0.f;
#pragma unroll 4
    for (int d = 0; d < 128; d += 4) {
      float4 wv = *(const float4*)(wr + d);
      bsum += tv[d] * wv.x + tv[d + 1] * wv.y + tv[d + 2] * wv.z + tv[d + 3] * wv.w;
    }
    if (half) { bpart[o] = bsum; }
    __syncthreads();
    if (!half) ws[BASE_ + (g * N_ + n) * D_ + o] = bias[o] + bsum + bpart[o];
  }

  // scatter LOO corrections into per-64-row-tile lists
  if (tid < 128) {
    int d = tid; int am = sam2[d]; float dl = sdl[d];
    int t = am >> 6;
    int slot = atomicAdd(&scnt[t], 1);
    int tile = (g == 0) ? (n * 32 + t) : (512 + n * 16 + t);
    int* hl = (int*)ws + HLIST_ + tile * 256;
    hl[slot * 2]     = (am & 63) | (d << 8);
    hl[slot * 2 + 1] = __float_as_int(dl);
  }
  __syncthreads();
  int tcount = g ? 16 : 32;
  if (tid < tcount) {
    int tile = (g == 0) ? (n * 32 + tid) : (512 + n * 16 + tid);
    ((int*)ws)[HCNT_ + tile] = scnt[tid];
  }
}

// ---------------------------------------------------------------------------
// Kernel 3: GEMM. 64-row tiles, grid 768 (1:1 with stats -> same-XCD L2 for
// xbf). K-loop FULLY unrolled with ALL 24 fragment loads (16 W + 8 x) issued
// before the first MFMA: one parallel vmcnt drain instead of 4 dependent
// batches (kernel is L2-latency-bound, R2 counters). launch_bounds(256,3)
// caps VGPR at 168 (grid 768 = exactly 3 blocks/CU anyway, no occupancy loss).
// Swapped MFMA operands (D=[o][xrow]) -> nontemporal dwordx4 y stores.
// All acc indices compile-time (rule 20: no scratch demotion).
// ---------------------------------------------------------------------------
__global__ __launch_bounds__(256, 3) void gemm_kernel(
    const float* __restrict__ W0, const float* __restrict__ W1,
    float* __restrict__ out, const float* __restrict__ ws) {
  int bid = blockIdx.x, tid = threadIdx.x;
  int g, n, r0, L; const float* W; float* y; const unsigned short* xbf;
  if (bid < 512) {
    g = 0; n = bid >> 5; r0 = (bid & 31) << 6; L = L0_; W = W0; y = out;
    xbf = (const unsigned short*)(ws + XBF_);
  } else {
    int b = bid - 512; g = 1; n = b >> 4; r0 = (b & 15) << 6; L = L1_; W = W1;
    y = out + (size_t)N_ * L0_ * D_;
    xbf = (const unsigned short*)(ws + XBF_) + (size_t)N_ * L0_ * D_;
  }

  int w = tid >> 6, lane = tid & 63, lm = lane & 15, lq = lane >> 4;
  int rsub = (w & 1) << 5, cw = (w >> 1) << 6;

  int hc = ((const int*)ws)[HCNT_ + bid];
  const int* hl = (const int*)ws + HLIST_ + bid * 256;

  const unsigned short* wbf = (const unsigned short*)(ws + WBF_) + g * 16384;
  const unsigned short* xb = xbf + (size_t)(n * L + r0 + rsub) * D_;

  // ---- issue ALL fragment loads (independent; one parallel drain) ----
  bf16x8 af[2][4];   // x rows  -> B operand
  bf16x8 bfr[4][4];  // W rows  -> A operand
#pragma unroll
  for (int kk = 0; kk < 4; kk++) {
    int ko = kk * 32 + lq * 8;
#pragma unroll
    for (int i = 0; i < 2; i++)
      af[i][kk] = __builtin_bit_cast(bf16x8,
          *(const ushortx8*)(xb + (size_t)(i * 16 + lm) * D_ + ko));
#pragma unroll
    for (int j = 0; j < 4; j++)
      bfr[j][kk] = __builtin_bit_cast(bf16x8,
          *(const ushortx8*)&wbf[(cw + j * 16 + lm) * 128 + ko]);
  }

  floatx4 acc[2][4];
#pragma unroll
  for (int i = 0; i < 2; i++)
#pragma unroll
    for (int j = 0; j < 4; j++) acc[i][j] = (floatx4){0.f, 0.f, 0.f, 0.f};

#pragma unroll
  for (int kk = 0; kk < 4; kk++)
#pragma unroll
    for (int i = 0; i < 2; i++)
#pragma unroll
      for (int j = 0; j < 4; j++)
        acc[i][j] = __builtin_amdgcn_mfma_f32_16x16x32_bf16(
            bfr[j][kk], af[i][kk], acc[i][j], 0, 0, 0);

  // sparse LOO corrections (fp32-exact). acc[i][j][r] covers
  // y[rsub+i*16+lm][cw+j*16+lq*4+r]; i unrolled, row predicate per lane.
  int off = 128 + (g << 7);
  for (int k = 0; k < hc; k++) {
    int e = hl[2 * k]; float dl = __int_as_float(hl[2 * k + 1]);
    int row = e & 63, d = e >> 8;
#pragma unroll
    for (int i = 0; i < 2; i++) {
      if (row == rsub + i * 16 + lm) {
#pragma unroll
        for (int j = 0; j < 4; j++)
#pragma unroll
          for (int r = 0; r < 4; r++)
            acc[i][j][r] += dl * W[(size_t)(cw + j * 16 + lq * 4 + r) * H_ + off + d];
      }
    }
  }

  // epilogue: base add (loaded late, after k-loop pressure) + NT store
  const float* bp = ws + BASE_ + (g * N_ + n) * D_;
  float* yb = y + (size_t)(n * L + r0 + rsub) * D_;
#pragma unroll
  for (int i = 0; i < 2; i++)
#pragma unroll
    for (int j = 0; j < 4; j++) {
      floatx4 bbj = *(const floatx4*)&bp[cw + j * 16 + lq * 4];
      floatx4 v = acc[i][j] + bbj;
      __builtin_nontemporal_store(v,
          (floatx4*)&yb[(size_t)(i * 16 + lm) * D_ + cw + j * 16 + lq * 4]);
    }
}

extern "C" void kernel_launch(void* const* d_in, const int* in_sizes, int n_in,
                              void* d_out, int out_size, void* d_ws, size_t ws_size,
                              hipStream_t stream) {
  const float* x0 = (const float*)d_in[0];
  const float* x1 = (const float*)d_in[1];
  const float* W0 = (const float*)d_in[2];
  const float* b0 = (const float*)d_in[3];
  const float* W1 = (const float*)d_in[4];
  const float* b1 = (const float*)d_in[5];
  float* out = (float*)d_out;
  float* ws  = (float*)d_ws;

  hipLaunchKernelGGL(stats_kernel, dim3(770), dim3(256), 0, stream, x0, x1, W0, W1, ws);
  hipLaunchKernelGGL(prep_kernel,  dim3(32),  dim3(256), 0, stream, W0, b0, W1, b1, ws);
  hipLaunchKernelGGL(gemm_kernel,  dim3(768), dim3(256), 0, stream, W0, W1, out, ws);
}